// Round 4
// baseline (113.564 us; speedup 1.0000x reference)
//
#include <hip/hip_runtime.h>
#include <hip/hip_cooperative_groups.h>
#include <hip/hip_bf16.h>
#include <float.h>

namespace cg = cooperative_groups;
typedef float f32x4 __attribute__((ext_vector_type(4)));

// ---------------- device helpers ----------------

// Argmax of R consecutive rows (row = t*batch + b) by one 64-lane wave.
// Writes ml[b*seq_len + t] (transposed). Strict '>' + lower-index tie-break
// reproduces first-occurrence argmax.
template <int R>
__device__ __forceinline__ void argmax_rows(const float* __restrict__ x,
                                            int* __restrict__ ml,
                                            int row0, int nrows,
                                            int seq_len, int batch, int vocab,
                                            int lane) {
    float best[R];
    int bidx[R];
#pragma unroll
    for (int r = 0; r < R; ++r) { best[r] = -FLT_MAX; bidx[r] = vocab; }

    const int vocab4 = vocab & ~3;
    for (int base = lane * 4; base < vocab4; base += 256) {
#pragma unroll
        for (int r = 0; r < R; ++r) {
            const int row = row0 + r;
            if (row >= nrows) continue;
            f32x4 v = *reinterpret_cast<const f32x4*>(x + (size_t)row * vocab + base);
#pragma unroll
            for (int j = 0; j < 4; ++j) {
                if (v[j] > best[r]) { best[r] = v[j]; bidx[r] = base + j; }
            }
        }
    }
    // Scalar tail (vocab % 4 != 0); tail indices exceed main-loop indices.
    for (int i = vocab4 + lane; i < vocab; i += 64) {
#pragma unroll
        for (int r = 0; r < R; ++r) {
            if (row0 + r >= nrows) continue;
            float v = x[(size_t)(row0 + r) * vocab + i];
            if (v > best[r]) { best[r] = v; bidx[r] = i; }
        }
    }

    // Wave butterfly reduce; larger value wins, tie -> lower index.
#pragma unroll
    for (int off = 32; off >= 1; off >>= 1) {
#pragma unroll
        for (int r = 0; r < R; ++r) {
            float ov = __shfl_down(best[r], off, 64);
            int oi = __shfl_down(bidx[r], off, 64);
            if (ov > best[r] || (ov == best[r] && oi < bidx[r])) {
                best[r] = ov; bidx[r] = oi;
            }
        }
    }

    if (lane == 0) {
#pragma unroll
        for (int r = 0; r < R; ++r) {
            const int row = row0 + r;
            if (row < nrows) {
                const int t = row / batch;
                const int b = row - t * batch;
                ml[(size_t)b * seq_len + t] = bidx[r];
            }
        }
    }
}

// Compact one batch row with 256 threads. tokens row pre-filled with -1.
__device__ __forceinline__ void compact_batch(const int* __restrict__ ml,
                                              const int* __restrict__ lengths,
                                              int blank,
                                              int* __restrict__ tokens,
                                              int* __restrict__ out_lengths,
                                              int b, int seq_len,
                                              int* warp_sums) {
    constexpr int MAXPER = 16;
    const int len = lengths[b];
    const int* row = ml + (size_t)b * seq_len;
    int* out = tokens + (size_t)b * seq_len;

    const int tid = threadIdx.x;
    const int nthr = blockDim.x;
    const int per = (seq_len + nthr - 1) / nthr;  // 8 for 2048/256

    const int t0 = tid * per;
    int vals[MAXPER];
    unsigned keep_mask = 0;
    int cnt = 0;
    int prev = (t0 == 0) ? -1 : ((t0 - 1 < seq_len) ? row[t0 - 1] : -1);
    for (int j = 0; j < per; ++j) {
        const int t = t0 + j;
        if (t >= seq_len) break;
        const int v = row[t];
        const bool valid = t < len;
        const bool k = valid && (v != blank) && (prev == blank || v != prev);
        vals[j] = v;
        if (k) { keep_mask |= (1u << j); ++cnt; }
        prev = v;
    }

    // Block-wide exclusive prefix sum (thread order).
    const int lane = tid & 63;
    const int wid = tid >> 6;
    int incl = cnt;
#pragma unroll
    for (int off = 1; off < 64; off <<= 1) {
        int n = __shfl_up(incl, off, 64);
        if (lane >= off) incl += n;
    }
    if (lane == 63) warp_sums[wid] = incl;
    __syncthreads();

    int wbase = 0;
    for (int w = 0; w < wid; ++w) wbase += warp_sums[w];
    int pos = wbase + incl - cnt;

    for (int j = 0; j < per; ++j) {
        if (keep_mask & (1u << j)) out[pos++] = vals[j];
    }

    if (tid == 0) {
        int total = 0;
        const int nwaves = nthr >> 6;
        for (int w = 0; w < nwaves; ++w) total += warp_sums[w];
        out_lengths[b] = total;
    }
}

// ---------------- fused cooperative kernel ----------------

template <int R>
__global__ __launch_bounds__(256, 4) void ctc_fused_kernel(
    const float* __restrict__ x,
    int* __restrict__ ml,
    const int* __restrict__ lengths,
    const int* __restrict__ blank_ptr,
    int* __restrict__ tokens,
    int* __restrict__ out_lengths,
    int seq_len, int batch, int vocab) {
    __shared__ int warp_sums[8];

    const int nrows = seq_len * batch;
    const int lane = threadIdx.x & 63;
    const int wavesPerBlk = blockDim.x >> 6;
    const int gwave = blockIdx.x * wavesPerBlk + (threadIdx.x >> 6);
    const int nwaves = gridDim.x * wavesPerBlk;
    const int ntasks = (nrows + R - 1) / R;

    // -1 fill of tokens, grid-strided.
    const int gtid = blockIdx.x * blockDim.x + threadIdx.x;
    const int gstride = gridDim.x * blockDim.x;
    for (int i = gtid; i < nrows; i += gstride) tokens[i] = -1;

    // Phase 1: argmax, grid-strided over R-row tasks.
    for (int tsk = gwave; tsk < ntasks; tsk += nwaves) {
        argmax_rows<R>(x, ml, tsk * R, nrows, seq_len, batch, vocab, lane);
    }

    cg::this_grid().sync();

    // Phase 2: one block per batch element.
    const int b = blockIdx.x;
    if (b < batch) {
        compact_batch(ml, lengths, *blank_ptr, tokens, out_lengths, b, seq_len,
                      warp_sums);
    }
}

// ---------------- fallback two-kernel path ----------------

template <int R>
__global__ __launch_bounds__(256) void ctc_argmax_kernel(
    const float* __restrict__ x, int* __restrict__ ml, int* __restrict__ tokens,
    int seq_len, int batch, int vocab) {
    const int nrows = seq_len * batch;
    const int lane = threadIdx.x & 63;
    const int wave = blockIdx.x * (blockDim.x >> 6) + (threadIdx.x >> 6);
    const int gtid = blockIdx.x * blockDim.x + threadIdx.x;
    const int gstride = gridDim.x * blockDim.x;
    for (int i = gtid; i < nrows; i += gstride) tokens[i] = -1;
    const int row0 = wave * R;
    if (row0 >= nrows) return;
    argmax_rows<R>(x, ml, row0, nrows, seq_len, batch, vocab, lane);
}

__global__ __launch_bounds__(256) void ctc_compact_kernel(
    const int* __restrict__ ml, const int* __restrict__ lengths,
    const int* __restrict__ blank_ptr, int* __restrict__ tokens,
    int* __restrict__ out_lengths, int seq_len, int batch) {
    __shared__ int warp_sums[8];
    const int b = blockIdx.x;
    if (b >= batch) return;
    compact_batch(ml, lengths, *blank_ptr, tokens, out_lengths, b, seq_len,
                  warp_sums);
}

// ---------------- host ----------------

extern "C" void kernel_launch(void* const* d_in, const int* in_sizes, int n_in,
                              void* d_out, int out_size, void* d_ws, size_t ws_size,
                              hipStream_t stream) {
    const float* x = (const float*)d_in[0];
    const int* lengths = (const int*)d_in[1];
    const int* blank_ptr = (const int*)d_in[2];

    const int batch = in_sizes[1];
    const int seq_len = (out_size - batch) / batch;  // tokens is (batch, seq_len)
    const int vocab = in_sizes[0] / (seq_len * batch);

    int* tokens = (int*)d_out;                                 // (batch, seq_len)
    int* out_lengths = (int*)d_out + (size_t)batch * seq_len;  // (batch,)
    int* ml = (int*)d_ws;                                      // (batch, seq_len)

    constexpr int R = 4;
    const int nrows = seq_len * batch;

    // Cooperative fused launch: 1024 blocks x 256 thr; __launch_bounds__(256,4)
    // guarantees 4 wg/CU residency on 256 CUs.
    int blocks = 1024;
    if (blocks < batch) blocks = batch;

    const float* x_ = x;
    int* ml_ = ml;
    const int* lengths_ = lengths;
    const int* blank_ = blank_ptr;
    int* tokens_ = tokens;
    int* olen_ = out_lengths;
    int seq_ = seq_len, batch_ = batch, vocab_ = vocab;
    void* args[] = {&x_, &ml_, &lengths_, &blank_, &tokens_, &olen_,
                    &seq_, &batch_, &vocab_};

    hipError_t err = hipLaunchCooperativeKernel(
        reinterpret_cast<void*>(ctc_fused_kernel<R>), dim3(blocks), dim3(256),
        args, 0, stream);

    if (err != hipSuccess) {
        // Fallback: proven two-kernel path.
        const int nwaves = (nrows + R - 1) / R;
        const int waves_per_block = 4;
        const int blocks1 = (nwaves + waves_per_block - 1) / waves_per_block;
        ctc_argmax_kernel<R><<<blocks1, waves_per_block * 64, 0, stream>>>(
            x, ml, tokens, seq_len, batch, vocab);
        ctc_compact_kernel<<<batch, 256, 0, stream>>>(
            ml, lengths, blank_ptr, tokens, out_lengths, seq_len, batch);
    }
}

// Round 5
// 27.406 us; speedup vs baseline: 4.1438x; 4.1438x over previous
//
#include <hip/hip_runtime.h>
#include <hip/hip_bf16.h>
#include <float.h>

typedef float f32x4 __attribute__((ext_vector_type(4)));

// Kernel 1: argmax over vocab for each (t, b) row, R rows per wave.
// x layout: (seq_len, batch, vocab) row-major; row = t*batch + b.
// KEY: rows with t >= lengths[b] are never consumed downstream (keep requires
// valid, and prev at time t<len only reads t-1<len), so we skip their 2KB
// load entirely. Expected read volume halves for uniform lengths.
// Output ml stored TRANSPOSED: ml[b*seq_len + t]. Also fills tokens with -1.
template <int R>
__global__ __launch_bounds__(256) void ctc_argmax_kernel(
    const float* __restrict__ x,
    int* __restrict__ ml,
    const int* __restrict__ lengths,
    int* __restrict__ tokens,
    int seq_len, int batch, int vocab) {
    const int nrows = seq_len * batch;

    // -1 fill of tokens (batch*seq_len ints), grid-strided.
    const int gtid = blockIdx.x * blockDim.x + threadIdx.x;
    const int gstride = gridDim.x * blockDim.x;
    for (int i = gtid; i < nrows; i += gstride) tokens[i] = -1;

    const int lane = threadIdx.x & 63;
    const int wave = blockIdx.x * (blockDim.x >> 6) + (threadIdx.x >> 6);
    const int row0 = wave * R;
    if (row0 >= nrows) return;

    // Per-row activity: row valid and t < lengths[b]. Wave-uniform.
    bool act[R];
    int tt[R], bb[R];
    bool any = false;
#pragma unroll
    for (int r = 0; r < R; ++r) {
        const int row = row0 + r;
        if (row < nrows) {
            const int t = row / batch;
            const int b = row - t * batch;
            tt[r] = t; bb[r] = b;
            act[r] = (t < lengths[b]);
        } else {
            act[r] = false; tt[r] = 0; bb[r] = 0;
        }
        any |= act[r];
    }
    if (!any) return;

    float best[R];
    int bidx[R];
#pragma unroll
    for (int r = 0; r < R; ++r) { best[r] = -FLT_MAX; bidx[r] = vocab; }

    const int vocab4 = vocab & ~3;
    for (int base = lane * 4; base < vocab4; base += 256) {
#pragma unroll
        for (int r = 0; r < R; ++r) {
            if (!act[r]) continue;
            f32x4 v = *reinterpret_cast<const f32x4*>(
                x + (size_t)(row0 + r) * vocab + base);
#pragma unroll
            for (int j = 0; j < 4; ++j) {
                if (v[j] > best[r]) { best[r] = v[j]; bidx[r] = base + j; }
            }
        }
    }
    // Scalar tail (vocab % 4 != 0); tail indices exceed main-loop indices,
    // strict '>' keeps the earlier occurrence.
    for (int i = vocab4 + lane; i < vocab; i += 64) {
#pragma unroll
        for (int r = 0; r < R; ++r) {
            if (!act[r]) continue;
            float v = x[(size_t)(row0 + r) * vocab + i];
            if (v > best[r]) { best[r] = v; bidx[r] = i; }
        }
    }

    // Wave butterfly reduce; larger value wins, tie -> lower index.
#pragma unroll
    for (int off = 32; off >= 1; off >>= 1) {
#pragma unroll
        for (int r = 0; r < R; ++r) {
            float ov = __shfl_down(best[r], off, 64);
            int oi = __shfl_down(bidx[r], off, 64);
            if (ov > best[r] || (ov == best[r] && oi < bidx[r])) {
                best[r] = ov; bidx[r] = oi;
            }
        }
    }

    if (lane == 0) {
#pragma unroll
        for (int r = 0; r < R; ++r) {
            if (act[r]) {
                ml[(size_t)bb[r] * seq_len + tt[r]] = bidx[r];
            }
        }
    }
}

// Kernel 2: per-batch removal of blanks and consecutive duplicates + left-pack.
// One block (256 threads) per batch element. tokens[] pre-filled with -1.
// ml entries at t >= lengths[b] may be garbage; keep=false there, and prev at
// any kept t reads t-1 < len, so garbage never influences the output.
__global__ __launch_bounds__(256) void ctc_compact_kernel(
    const int* __restrict__ ml,
    const int* __restrict__ lengths,
    const int* __restrict__ blank_ptr,
    int* __restrict__ tokens,
    int* __restrict__ out_lengths,
    int seq_len, int batch) {
    constexpr int MAXPER = 16;
    const int b = blockIdx.x;
    if (b >= batch) return;
    const int blank = *blank_ptr;
    const int len = lengths[b];
    const int* row = ml + (size_t)b * seq_len;
    int* out = tokens + (size_t)b * seq_len;

    const int tid = threadIdx.x;
    const int nthr = blockDim.x;
    const int per = (seq_len + nthr - 1) / nthr;  // 8 for 2048/256

    const int t0 = tid * per;
    int vals[MAXPER];
    unsigned keep_mask = 0;
    int cnt = 0;
    int prev = (t0 == 0) ? -1 : ((t0 - 1 < seq_len) ? row[t0 - 1] : -1);
    for (int j = 0; j < per; ++j) {
        const int t = t0 + j;
        if (t >= seq_len) break;
        const int v = row[t];
        const bool valid = t < len;
        const bool k = valid && (v != blank) && (prev == blank || v != prev);
        vals[j] = v;
        if (k) { keep_mask |= (1u << j); ++cnt; }
        prev = v;
    }

    // Block-wide exclusive prefix sum of cnt (thread order).
    __shared__ int warp_sums[8];
    const int lane = tid & 63;
    const int wid = tid >> 6;
    int incl = cnt;
#pragma unroll
    for (int off = 1; off < 64; off <<= 1) {
        int n = __shfl_up(incl, off, 64);
        if (lane >= off) incl += n;
    }
    if (lane == 63) warp_sums[wid] = incl;
    __syncthreads();

    int wbase = 0;
    for (int w = 0; w < wid; ++w) wbase += warp_sums[w];
    int pos = wbase + incl - cnt;  // exclusive prefix for this thread

    for (int j = 0; j < per; ++j) {
        if (keep_mask & (1u << j)) out[pos++] = vals[j];
    }

    if (tid == 0) {
        int total = 0;
        const int nwaves = nthr >> 6;
        for (int w = 0; w < nwaves; ++w) total += warp_sums[w];
        out_lengths[b] = total;
    }
}

extern "C" void kernel_launch(void* const* d_in, const int* in_sizes, int n_in,
                              void* d_out, int out_size, void* d_ws, size_t ws_size,
                              hipStream_t stream) {
    const float* x = (const float*)d_in[0];
    const int* lengths = (const int*)d_in[1];
    const int* blank_ptr = (const int*)d_in[2];

    const int batch = in_sizes[1];
    const int seq_len = (out_size - batch) / batch;      // tokens is (batch, seq_len)
    const int vocab = in_sizes[0] / (seq_len * batch);

    int* tokens = (int*)d_out;                                  // (batch, seq_len)
    int* out_lengths = (int*)d_out + (size_t)batch * seq_len;   // (batch,)
    int* ml = (int*)d_ws;                                       // (batch, seq_len)

    // Kernel 1: R rows per wave, 4 waves per 256-thread block.
    constexpr int R = 4;
    const int nrows = seq_len * batch;
    const int ntasks = (nrows + R - 1) / R;
    const int waves_per_block = 4;
    const int blocks1 = (ntasks + waves_per_block - 1) / waves_per_block;
    ctc_argmax_kernel<R><<<blocks1, waves_per_block * 64, 0, stream>>>(
        x, ml, lengths, tokens, seq_len, batch, vocab);

    // Kernel 2: one block per batch element.
    ctc_compact_kernel<<<batch, 256, 0, stream>>>(
        ml, lengths, blank_ptr, tokens, out_lengths, seq_len, batch);
}